// Round 4
// baseline (21.261 us; speedup 1.0000x reference)
//
#include <hip/hip_runtime.h>

#define N_SEQS 2048
#define SEQ_LEN 512
#define NAA 20
#define NS 21                       // states incl. gap (pad bin)
#define MPOS 100
#define NPAIRS 4950                 // 100*99/2
#define WPB 4                       // pairs (waves) per block
#define MI_BLOCKS ((NPAIRS + WPB - 1) / WPB)   // 1238
#define K2_GRID (SEQ_LEN + MI_BLOCKS)          // 1750

// ---------------------------------------------------------------------------
// K1: pack msa (int32 row-major) -> cols (uint8 column-major [C][2048]).
// 512 blocks x 4 rows; coalesced int4 row reads, scattered byte writes.
// ---------------------------------------------------------------------------
__global__ __launch_bounds__(256) void pack_kernel(const int* __restrict__ msa,
                                                   unsigned char* __restrict__ cols,
                                                   int full) {
    const int tid = threadIdx.x;
    const int r0 = blockIdx.x * 4;
    const int r = tid >> 6;          // 0..3
    const int c0 = (tid & 63) * 8;   // 0..504
    const int row = r0 + r;
    const int4* src = (const int4*)(msa + (size_t)row * SEQ_LEN + c0);
    int4 v0 = src[0], v1 = src[1];
    int v[8] = {v0.x, v0.y, v0.z, v0.w, v1.x, v1.y, v1.z, v1.w};
    if (full) {
#pragma unroll
        for (int k = 0; k < 8; ++k)
            cols[(size_t)(c0 + k) * N_SEQS + row] = (unsigned char)v[k];
    } else if (c0 < MPOS) {
#pragma unroll
        for (int k = 0; k < 8; ++k)
            if (c0 + k < MPOS)
                cols[(size_t)(c0 + k) * N_SEQS + row] = (unsigned char)v[k];
    }
}

// ---------------------------------------------------------------------------
// K2: blocks 0..511 = per-position pssm/cons + MI zeroing (race-free split);
//     blocks 512..1749 = MI pairs, one pair per wave, wave-private LDS hist.
// ---------------------------------------------------------------------------
__global__ __launch_bounds__(256) void main_kernel(const int* __restrict__ msa,
                                                   const float* __restrict__ pc,
                                                   const unsigned char* __restrict__ cols,
                                                   int full,
                                                   float* __restrict__ pssm,
                                                   float* __restrict__ cons,
                                                   float* __restrict__ mi) {
    __shared__ int hist[WPB][NS * NS];      // 7056 B
    __shared__ float ra_s[WPB][NAA];
    __shared__ float cb_s[WPB][NAA];

    const int tid = threadIdx.x;
    const int w = tid >> 6;
    const int lane = tid & 63;
    const int bid = blockIdx.x;

    if (bid < SEQ_LEN) {
        // ------------------------- position part -------------------------
        const int i = bid;
        float* rowp = mi + (size_t)i * SEQ_LEN;
        if (i < MPOS) {
            // MI blocks write ALL off-diagonal [0..100)x[0..100); we own the rest
            for (int idx = tid; idx < SEQ_LEN - MPOS; idx += 256)
                rowp[MPOS + idx] = 0.f;
            if (tid == 0) rowp[i] = 0.f;
        } else {
            if (tid < SEQ_LEN / 4)
                ((float4*)rowp)[tid] = make_float4(0.f, 0.f, 0.f, 0.f);
        }

        int* h = hist[w];
        if (lane < NS) h[lane] = 0;     // wave-private: no barrier needed yet

        int vals[8];
        if (full) {
            uint2 dv = *(const uint2*)(cols + (size_t)i * N_SEQS + tid * 8);
            unsigned long long x = ((unsigned long long)dv.y << 32) | dv.x;
#pragma unroll
            for (int k = 0; k < 8; ++k) vals[k] = (int)((x >> (8 * k)) & 0xFF);
        } else {
#pragma unroll
            for (int k = 0; k < 8; ++k)
                vals[k] = msa[(size_t)(tid + 256 * k) * SEQ_LEN + i];
        }
#pragma unroll
        for (int k = 0; k < 8; ++k) atomicAdd(&h[vals[k]], 1);
        __syncthreads();

        if (tid < NAA) {
            int c = hist[0][tid] + hist[1][tid] + hist[2][tid] + hist[3][tid];
            cb_s[0][tid] = (float)c;
            float pcnt = 0.01f * pc[0];
            float freq = ((float)c + pcnt) / (2048.0f + pcnt * 20.0f);
            pssm[i * NAA + tid] = __logf(freq * 20.0f + 1e-10f);
        }
        __syncthreads();

        if (tid < 64) {
            float fc = (tid < NAA) ? cb_s[0][tid] : 0.f;
            float tot = fc;
#pragma unroll
            for (int off = 32; off; off >>= 1) tot += __shfl_xor(tot, off, 64);
            float ts = fmaxf(tot, 1.f);
            float f = __fdividef(fc, ts);
            float term = (tid < NAA) ? -f * __log2f(f + 1e-10f) : 0.f;
#pragma unroll
            for (int off = 32; off; off >>= 1) term += __shfl_xor(term, off, 64);
            if (tid == 0)
                cons[i] = (tot > 0.f) ? (1.f - term * 0.2313782131597592f) : 0.f;
        }
    } else {
        // ---------------------------- MI part ----------------------------
        int t = (bid - SEQ_LEN) * WPB + w;
        const bool active = (t < NPAIRS);
        if (!active) t = 0;

        int i = (int)((199.0f - sqrtf(39601.0f - 8.0f * (float)t)) * 0.5f);
        if (i < 0) i = 0;
        while ((i + 1) * (198 - i) / 2 <= t) ++i;
        while (i * (199 - i) / 2 > t) --i;
        const int j = i + 1 + (t - i * (199 - i) / 2);

        int* h = hist[w];
#pragma unroll
        for (int u = 0; u < 7; ++u) {
            int k = lane + 64 * u;
            if (k < NS * NS) h[k] = 0;
        }

        if (active) {
            const uint4* ci = (const uint4*)(cols + (size_t)i * N_SEQS + lane * 32);
            const uint4* cj = (const uint4*)(cols + (size_t)j * N_SEQS + lane * 32);
            uint4 A0 = ci[0], A1 = ci[1];
            uint4 B0 = cj[0], B1 = cj[1];
            unsigned int aw[8] = {A0.x, A0.y, A0.z, A0.w, A1.x, A1.y, A1.z, A1.w};
            unsigned int bw[8] = {B0.x, B0.y, B0.z, B0.w, B1.x, B1.y, B1.z, B1.w};
#pragma unroll
            for (int q = 0; q < 8; ++q) {
                unsigned int av = aw[q], bv = bw[q];
#pragma unroll
                for (int byte = 0; byte < 4; ++byte) {
                    int a = (av >> (8 * byte)) & 0xFF;
                    int b = (bv >> (8 * byte)) & 0xFF;
                    atomicAdd(&h[a * NS + b], 1);   // padded: no bounds check
                }
            }
        }

        // wave-local marginals (no block barrier: hist[w] is wave-private)
        if (lane < NAA) {
            int s = 0;
#pragma unroll
            for (int b = 0; b < NAA; ++b) s += h[lane * NS + b];
            ra_s[w][lane] = (float)s;
        } else if (lane >= 32 && lane < 32 + NAA) {
            int c = lane - 32, s = 0;
#pragma unroll
            for (int a = 0; a < NAA; ++a) s += h[a * NS + c];
            cb_s[w][c] = (float)s;
        }

        float tot = 0.f;
#pragma unroll
        for (int a = 0; a < NAA; ++a) tot += ra_s[w][a];
        const float ts = fmaxf(tot, 1.f);
        const float inv = __fdividef(1.f, ts);

        float part = 0.f;
#pragma unroll
        for (int u = 0; u < 7; ++u) {
            int k = lane + 64 * u;
            if (k < NAA * NAA) {
                int row = k / NAA;
                int col = k - row * NAA;
                int J = h[row * NS + col];
                if (J > 0) {
                    float p = (float)J * inv;
                    float pi = ra_s[w][row] * inv;
                    float pj = cb_s[w][col] * inv;
                    float denom = fmaxf(pi * pj, 1e-30f);
                    part += p * __log2f(__fdividef(p, denom) + 1e-10f);
                }
            }
        }
#pragma unroll
        for (int off = 32; off; off >>= 1) part += __shfl_down(part, off, 64);

        if (active && lane == 0) {
            float m = (tot > 0.f) ? part : 0.f;
            mi[(size_t)i * SEQ_LEN + j] = m;
            mi[(size_t)j * SEQ_LEN + i] = m;
        }
    }
}

// ---------------------------------------------------------------------------
extern "C" void kernel_launch(void* const* d_in, const int* in_sizes, int n_in,
                              void* d_out, int out_size, void* d_ws, size_t ws_size,
                              hipStream_t stream) {
    const int* msa = (const int*)d_in[0];
    const float* pc = (const float*)d_in[1];

    float* pssm = (float*)d_out;         // 512*20
    float* cons = pssm + SEQ_LEN * NAA;  // 512
    float* mi = cons + SEQ_LEN;          // 512*512

    unsigned char* cols = (unsigned char*)d_ws;
    const int full = (ws_size >= (size_t)SEQ_LEN * N_SEQS) ? 1 : 0;  // 1 MB

    pack_kernel<<<SEQ_LEN, 256, 0, stream>>>(msa, cols, full);
    main_kernel<<<K2_GRID, 256, 0, stream>>>(msa, pc, cols, full, pssm, cons, mi);
}

// Round 5
// 19.637 us; speedup vs baseline: 1.0827x; 1.0827x over previous
//
#include <hip/hip_runtime.h>

#define N_SEQS 2048
#define SEQ_LEN 512
#define NAA 20
#define NS 21                        // states incl. gap (pad bin)
#define MPOS 100
#define G 4                          // position-group size
#define NG (MPOS / G)                // 25 groups
#define NTILE (NG * (NG + 1) / 2)    // 325 tile-pairs (ti<=tj)
#define POSB (SEQ_LEN / 8)           // 64 pos blocks (8 positions each)
#define HBINS (NS * NS)              // 441

// ---------------------------------------------------------------------------
// Single fused kernel.
//  blocks [0, NTILE)        : MI 4x4 tile-pairs, 16 LDS histograms, direct msa reads
//  blocks [NTILE, NTILE+64) : 8 positions each -> pssm, conservation, MI-row zeroing
// ---------------------------------------------------------------------------
__global__ __launch_bounds__(256) void fused_kernel(const int* __restrict__ msa,
                                                    const float* __restrict__ pc,
                                                    float* __restrict__ pssm,
                                                    float* __restrict__ cons,
                                                    float* __restrict__ mi) {
    __shared__ int h_s[16 * HBINS];          // 28224 B
    __shared__ float ra_s[4][NAA], cb_s[4][NAA];

    const int tid = threadIdx.x;
    const int w = tid >> 6;
    const int lane = tid & 63;
    const int bid = blockIdx.x;

    if (bid < NTILE) {
        // ======================== MI tile-pair part ========================
        // decode (ti <= tj) from linear tile index
        int t = bid, ti = 0, off = 0;
        while (off + (NG - ti) <= t) { off += NG - ti; ++ti; }
        const int tj = ti + (t - off);
        const int i0 = ti * G, j0 = tj * G;
        const bool diag = (ti == tj);

        for (int k = tid; k < 16 * HBINS; k += 256) h_s[k] = 0;
        __syncthreads();

#pragma unroll
        for (int k = 0; k < 8; ++k) {
            const int s = tid + (k << 8);
            const int* rp = msa + (size_t)s * SEQ_LEN;
            const int4 va = *(const int4*)(rp + i0);
            const int4 vb = *(const int4*)(rp + j0);
            const int A0 = va.x * 21, A1 = va.y * 21, A2 = va.z * 21, A3 = va.w * 21;
            const int B0 = vb.x, B1 = vb.y, B2 = vb.z, B3 = vb.w;
            // constants (pi*1764 + pj*441) fold into ds_atomic offset immediates
            atomicAdd(&h_s[0 * 1764 + 0 * 441 + A0 + B0], 1);
            atomicAdd(&h_s[0 * 1764 + 1 * 441 + A0 + B1], 1);
            atomicAdd(&h_s[0 * 1764 + 2 * 441 + A0 + B2], 1);
            atomicAdd(&h_s[0 * 1764 + 3 * 441 + A0 + B3], 1);
            atomicAdd(&h_s[1 * 1764 + 0 * 441 + A1 + B0], 1);
            atomicAdd(&h_s[1 * 1764 + 1 * 441 + A1 + B1], 1);
            atomicAdd(&h_s[1 * 1764 + 2 * 441 + A1 + B2], 1);
            atomicAdd(&h_s[1 * 1764 + 3 * 441 + A1 + B3], 1);
            atomicAdd(&h_s[2 * 1764 + 0 * 441 + A2 + B0], 1);
            atomicAdd(&h_s[2 * 1764 + 1 * 441 + A2 + B1], 1);
            atomicAdd(&h_s[2 * 1764 + 2 * 441 + A2 + B2], 1);
            atomicAdd(&h_s[2 * 1764 + 3 * 441 + A2 + B3], 1);
            atomicAdd(&h_s[3 * 1764 + 0 * 441 + A3 + B0], 1);
            atomicAdd(&h_s[3 * 1764 + 1 * 441 + A3 + B1], 1);
            atomicAdd(&h_s[3 * 1764 + 2 * 441 + A3 + B2], 1);
            atomicAdd(&h_s[3 * 1764 + 3 * 441 + A3 + B3], 1);
        }
        __syncthreads();

        // finish: wave w handles pairs 4w..4w+3
#pragma unroll
        for (int q = 0; q < 4; ++q) {
            const int p = w * 4 + q;
            const int pi = p >> 2, pj = p & 3;
            if (diag && pi >= pj) continue;          // wave-uniform branch
            const int* h = h_s + p * HBINS;

            if (lane < NAA) {
                int s = 0;
#pragma unroll
                for (int b = 0; b < NAA; ++b) s += h[lane * NS + b];
                ra_s[w][lane] = (float)s;
            } else if (lane >= 32 && lane < 32 + NAA) {
                int c = lane - 32, s = 0;
#pragma unroll
                for (int a = 0; a < NAA; ++a) s += h[a * NS + c];
                cb_s[w][c] = (float)s;
            }

            float tot = 0.f;
#pragma unroll
            for (int a = 0; a < NAA; ++a) tot += ra_s[w][a];
            const float ts = fmaxf(tot, 1.f);
            const float inv = __fdividef(1.f, ts);

            float part = 0.f;
#pragma unroll
            for (int u = 0; u < 7; ++u) {
                const int k = lane + 64 * u;
                if (k < NAA * NAA) {
                    const int row = k / NAA;
                    const int col = k - row * NAA;
                    const int J = h[row * NS + col];
                    if (J > 0) {
                        float pp = (float)J * inv;
                        float pi_f = ra_s[w][row] * inv;
                        float pj_f = cb_s[w][col] * inv;
                        float denom = fmaxf(pi_f * pj_f, 1e-30f);
                        part += pp * __log2f(__fdividef(pp, denom) + 1e-10f);
                    }
                }
            }
#pragma unroll
            for (int o = 32; o; o >>= 1) part += __shfl_down(part, o, 64);

            if (lane == 0) {
                const float m = (tot > 0.f) ? part : 0.f;
                mi[(size_t)(i0 + pi) * SEQ_LEN + (j0 + pj)] = m;
                mi[(size_t)(j0 + pj) * SEQ_LEN + (i0 + pi)] = m;
            }
        }
    } else {
        // ========================== position part ==========================
        const int pb = bid - NTILE;          // 0..63
        const int i0 = pb * 8;

        // zero MI rows i0..i0+7 (race-free: MI blocks own off-diag [0,100)^2)
        for (int r = 0; r < 8; ++r) {
            const int i = i0 + r;
            float* rowp = mi + (size_t)i * SEQ_LEN;
            if (i < MPOS) {
                for (int c = MPOS + tid; c < SEQ_LEN; c += 256) rowp[c] = 0.f;
                if (tid == 0) rowp[i] = 0.f;
            } else {
                if (tid < SEQ_LEN / 4)
                    ((float4*)rowp)[tid] = make_float4(0.f, 0.f, 0.f, 0.f);
            }
        }

        // wave-replicated 8x21 histograms
        for (int k = tid; k < 4 * 8 * NS; k += 256) h_s[k] = 0;
        __syncthreads();

        int* h = h_s + w * (8 * NS);
#pragma unroll
        for (int k = 0; k < 8; ++k) {
            const int s = tid + (k << 8);
            const int* rp = msa + (size_t)s * SEQ_LEN + i0;
            const int4 v0 = *(const int4*)rp;
            const int4 v1 = *(const int4*)(rp + 4);
            atomicAdd(&h[0 * NS + v0.x], 1);
            atomicAdd(&h[1 * NS + v0.y], 1);
            atomicAdd(&h[2 * NS + v0.z], 1);
            atomicAdd(&h[3 * NS + v0.w], 1);
            atomicAdd(&h[4 * NS + v1.x], 1);
            atomicAdd(&h[5 * NS + v1.y], 1);
            atomicAdd(&h[6 * NS + v1.z], 1);
            atomicAdd(&h[7 * NS + v1.w], 1);
        }
        __syncthreads();

        // merge replicas + pssm (160 entries: 8 positions x 20 aa)
        float* cntf = (float*)(h_s + 1024);   // beyond the 672 used ints
        if (tid < 8 * NAA) {
            const int p = tid / NAA, a = tid - p * NAA;
            const int idx = p * NS + a;
            const int c = h_s[idx] + h_s[168 + idx] + h_s[336 + idx] + h_s[504 + idx];
            cntf[tid] = (float)c;
            const float pcnt = 0.01f * pc[0];
            const float freq = __fdividef((float)c + pcnt, 2048.0f + pcnt * 20.0f);
            pssm[(size_t)(i0 + p) * NAA + a] = __logf(freq * 20.0f + 1e-10f);
        }
        __syncthreads();

        // conservation: 8 groups of 32 threads
        const int p = tid >> 5, l = tid & 31;
        const float fc = (l < NAA) ? cntf[p * NAA + l] : 0.f;
        float tt = fc;
#pragma unroll
        for (int o = 16; o; o >>= 1) tt += __shfl_xor(tt, o, 32);
        const float ts2 = fmaxf(tt, 1.f);
        const float f = __fdividef(fc, ts2);
        float term = (l < NAA) ? -f * __log2f(f + 1e-10f) : 0.f;
#pragma unroll
        for (int o = 16; o; o >>= 1) term += __shfl_xor(term, o, 32);
        if (l == 0)
            cons[i0 + p] = (tt > 0.f) ? (1.f - term * 0.2313782131597592f) : 0.f;
    }
}

// ---------------------------------------------------------------------------
extern "C" void kernel_launch(void* const* d_in, const int* in_sizes, int n_in,
                              void* d_out, int out_size, void* d_ws, size_t ws_size,
                              hipStream_t stream) {
    const int* msa = (const int*)d_in[0];
    const float* pc = (const float*)d_in[1];

    float* pssm = (float*)d_out;         // 512*20
    float* cons = pssm + SEQ_LEN * NAA;  // 512
    float* mi = cons + SEQ_LEN;          // 512*512

    fused_kernel<<<NTILE + POSB, 256, 0, stream>>>(msa, pc, pssm, cons, mi);
}